// Round 1
// 202.338 us; speedup vs baseline: 1.0176x; 1.0176x over previous
//
#include <hip/hip_runtime.h>
#include <stdint.h>

// Problem constants (fixed by reference setup_inputs)
#define BB 8
#define SS 2048
#define DD 2048
#define EE 8
#define CHUNKS 256
#define ROWS 8    // SS / CHUNKS

typedef float f4 __attribute__((ext_vector_type(4)));

// Kernel 1: stream x (fp32). Per block = one (b, chunk of 8 rows).
// Hot loop ONLY accumulates xsum[8] per thread (column sums over the 8 rows);
// dot with W is deferred to the epilogue (dot is linear in the row sum).
__global__ __launch_bounds__(256) void k_partial(const float* __restrict__ x,
                                                 const float* __restrict__ W,
                                                 float* __restrict__ pout) {
    const int t = threadIdx.x;
    const int bid = blockIdx.x;
    const int b = bid >> 8;              // / CHUNKS
    const int chunk = bid & (CHUNKS - 1);
    const int d0 = t * 8;                // 256 threads * 8 floats = full D row

    const float* xp = x + ((size_t)b * SS + (size_t)chunk * ROWS) * DD + d0;

    float xsum[8] = {0.f, 0.f, 0.f, 0.f, 0.f, 0.f, 0.f, 0.f};
#pragma unroll
    for (int r = 0; r < ROWS; ++r) {
        f4 xa = *(const f4*)(xp + (size_t)r * DD);
        f4 xb = *(const f4*)(xp + (size_t)r * DD + 4);
#pragma unroll
        for (int j = 0; j < 4; ++j) { xsum[j] += xa[j]; xsum[4 + j] += xb[j]; }
    }

    // Epilogue: 9 partials = 8 expert dots + total x sum (W is L2-hot, 64 KB)
    float vals[9];
    float xtot = 0.f;
#pragma unroll
    for (int j = 0; j < 8; ++j) xtot += xsum[j];
#pragma unroll
    for (int e = 0; e < 8; ++e) {
        f4 wa = *(const f4*)(W + e * DD + d0);
        f4 wb = *(const f4*)(W + e * DD + d0 + 4);
        float acc = 0.f;
#pragma unroll
        for (int j = 0; j < 4; ++j) acc = fmaf(xsum[j], wa[j], acc);
#pragma unroll
        for (int j = 0; j < 4; ++j) acc = fmaf(xsum[4 + j], wb[j], acc);
        vals[e] = acc;
    }
    vals[8] = xtot;

    // wave-level butterfly reduce of 9 values
#pragma unroll
    for (int off = 32; off >= 1; off >>= 1) {
#pragma unroll
        for (int j = 0; j < 9; ++j) vals[j] += __shfl_xor(vals[j], off, 64);
    }

    __shared__ float lw[4][9];
    const int lane = t & 63, wid = t >> 6;
    if (lane == 0) {
#pragma unroll
        for (int j = 0; j < 9; ++j) lw[wid][j] = vals[j];
    }
    __syncthreads();
    if (t < 9) {
        pout[bid * 9 + t] = lw[0][t] + lw[1][t] + lw[2][t] + lw[3][t];
    }
}

// Kernel 2: single block, fully parallel/vectorized.
// Phase A: reduce 2048 partial records (9 floats each, 72 KB): thread t owns
//          8 consecutive records (18 f4 loads, same batch b = t>>5),
//          then a 5-stage shfl_xor tree across its 32-thread group.
// Phase B: W row stats — thread owns 64 contiguous floats (16 f4 loads).
// Phase C: 8 threads: scores -> softmax -> top2 -> outputs.
__global__ __launch_bounds__(256) void k_finish(const float* __restrict__ pin,
                                                const float* __restrict__ W,
                                                const float* __restrict__ gain,
                                                const float* __restrict__ istd,
                                                const float* __restrict__ noise,
                                                float* __restrict__ out) {
    const int t = threadIdx.x;
    const int l = t & 31;
    const int g = t >> 5;   // group 0..7: batch index in phase A, expert index in phase B

    __shared__ float sdot[BB][9];
    __shared__ float smean[EE], sscale[EE];

    // ---- Phase A
    float sums[9] = {0.f, 0.f, 0.f, 0.f, 0.f, 0.f, 0.f, 0.f, 0.f};
    {
        const f4* pa = (const f4*)(pin + (size_t)t * 72);
#pragma unroll
        for (int i = 0; i < 18; ++i) {
            f4 v = pa[i];
#pragma unroll
            for (int j = 0; j < 4; ++j) sums[(i * 4 + j) % 9] += v[j];
        }
    }
#pragma unroll
    for (int off = 16; off >= 1; off >>= 1) {
#pragma unroll
        for (int j = 0; j < 9; ++j) sums[j] += __shfl_xor(sums[j], off, 64);
    }
    if (l < 9) sdot[g][l] = sums[l];

    // ---- Phase B: W row stats (mean, unbiased std + EPS, keep_init scale)
    {
        float s = 0.f, q = 0.f;
        const f4* wp = (const f4*)(W + (size_t)g * DD + l * 64);
#pragma unroll
        for (int i = 0; i < 16; ++i) {
            f4 v = wp[i];
#pragma unroll
            for (int j = 0; j < 4; ++j) { s += v[j]; q = fmaf(v[j], v[j], q); }
        }
#pragma unroll
        for (int off = 16; off >= 1; off >>= 1) {
            s += __shfl_xor(s, off, 64);
            q += __shfl_xor(q, off, 64);
        }
        if (l == 0) {
            const float mean = s / (float)DD;
            float var = (q - (float)DD * mean * mean) / (float)(DD - 1);
            var = fmaxf(var, 0.f);
            const float stdv = sqrtf(var) + 1e-5f;   // torch-style unbiased std + EPS
            smean[g] = mean;
            sscale[g] = istd[g] / stdv * gain[g];
        }
    }
    __syncthreads();

    // ---- Phase C: one thread per batch row
    if (t < BB) {
        const int b = t;
        const float xtot = sdot[b][8];
        float p[EE];
        float m = -1e30f;
#pragma unroll
        for (int e = 0; e < EE; ++e) {
            float sc = sscale[e] * (sdot[b][e] - smean[e] * xtot) * (1.f / (float)SS)
                     + noise[b * EE + e];
            p[e] = sc;
            m = fmaxf(m, sc);
        }
        float sum = 0.f;
#pragma unroll
        for (int e = 0; e < EE; ++e) { p[e] = __expf(p[e] - m); sum += p[e]; }
        const float inv = 1.f / sum;
#pragma unroll
        for (int e = 0; e < EE; ++e) p[e] *= inv;

        // top-2, ties -> lowest index first (strict >, ascending scan)
        int i1 = 0;
#pragma unroll
        for (int e = 1; e < EE; ++e) if (p[e] > p[i1]) i1 = e;
        int i2 = (i1 == 0) ? 1 : 0;
#pragma unroll
        for (int e = 0; e < EE; ++e) if (e != i1 && p[e] > p[i2]) i2 = e;

        // combine tensor [B,E]
#pragma unroll
        for (int e = 0; e < EE; ++e) {
            float v = (e == i1) ? p[i1] : ((e == i2) ? p[i2] : 0.f);
            out[b * EE + e] = v;
        }
        // indices [B,2] as numeric values
        out[64 + b * 2 + 0] = (float)i1;
        out[64 + b * 2 + 1] = (float)i2;
        // topk gate scores [B,2]
        out[80 + b * 2 + 0] = p[i1];
        out[80 + b * 2 + 1] = p[i2];
    }
}

extern "C" void kernel_launch(void* const* d_in, const int* in_sizes, int n_in,
                              void* d_out, int out_size, void* d_ws, size_t ws_size,
                              hipStream_t stream) {
    const float* x     = (const float*)d_in[0];
    const float* W     = (const float*)d_in[1];
    const float* gain  = (const float*)d_in[2];
    const float* istd  = (const float*)d_in[3];
    const float* noise = (const float*)d_in[4];
    // d_in[5] = top_k (==2) — hardcoded per reference.

    float* pbuf = (float*)d_ws;          // BB*CHUNKS*9 floats = 72 KB
    float* out = (float*)d_out;          // 96 fp32

    k_partial<<<dim3(BB * CHUNKS), dim3(256), 0, stream>>>(x, W, pbuf);
    k_finish<<<dim3(1), dim3(256), 0, stream>>>(pbuf, W, gain, istd, noise, out);
}